// Round 8
// baseline (525.548 us; speedup 1.0000x reference)
//
#include <hip/hip_runtime.h>
#include <hip/hip_bf16.h>
#include <math.h>

// ---------------------------------------------------------------------------
// ChunkGatedAttentionUnit: B=2, S=4096, H=1024, D=2048, CHUNK=128, nC=32
// Round 8: 256x256 2-phase counted-vmcnt core (T3/T4), unit-contiguous LDS
// ([kk-half][row][32] w/ 16B-slot XOR swizzle), vmcnt(4) per phase (never 0
// in loop), 1 barrier/phase, 32 MFMA/phase under setprio. All GEMMs on it.
// ---------------------------------------------------------------------------

typedef __bf16 bf16_t;
typedef __bf16 bf16x8 __attribute__((ext_vector_type(8)));
typedef __bf16 bf16x4 __attribute__((ext_vector_type(4)));
typedef float f32x4 __attribute__((ext_vector_type(4)));

#define NB_ 2
#define SEQ 4096
#define HID 1024
#define DD 2048
#define BS 8192
#define LDS_CORE 131072
#define SP 264

__device__ __forceinline__ void async16(const void* g, void* l) {
  __builtin_amdgcn_global_load_lds(
      (const __attribute__((address_space(1))) void*)g,
      (__attribute__((address_space(3))) void*)l, 16, 0, 0);
}

#define VMW4 asm volatile("s_waitcnt vmcnt(4)" ::: "memory")
#define VMW0 asm volatile("s_waitcnt vmcnt(0)" ::: "memory")
#define BARR __builtin_amdgcn_s_barrier()
#define FEN asm volatile("" ::: "memory")

// C[256,256] = A[256,K] @ B[256,K]^T, BK=64 in two kk=32 phases.
// LDS: 2 tile-buffers x 2 units; unit h = [A 256x32][B 256x32] (32KB, linear
// dest). 16B slots XOR-swizzled by row&3 (inverse pre-applied on gload src).
// Steady state: vmcnt(4) per phase confirms the unit issued 2 phases ago.
__device__ __forceinline__ void core256(const bf16_t* __restrict__ A, int lda,
                                        const bf16_t* __restrict__ B, int ldb, int nt,
                                        bf16_t* lds, f32x4 (&acc)[8][4]) {
  constexpr int UE = 16384;   // unit elems
  constexpr int BUFE = 32768; // per-K-tile buffer elems
  const int t = threadIdx.x, lane = t & 63, w = t >> 6;
  const int wm = w >> 2, wn = w & 3;
  const int lr = lane & 15, lg = lane >> 4;
  const int sw8 = (lg ^ (lr & 3)) * 8;
  int aOff[8], bOff[4];
#pragma unroll
  for (int f = 0; f < 8; ++f) aOff[f] = (wm * 128 + f * 16 + lr) * 32 + sw8;
#pragma unroll
  for (int n = 0; n < 4; ++n) bOff[n] = 8192 + (wn * 64 + n * 16 + lr) * 32 + sw8;
  const int ssl = ((t & 3) ^ ((t >> 2) & 3)) * 8;
  const int r0 = t >> 2;
  const int srcA0 = r0 * lda + ssl, srcA1 = (128 + r0) * lda + ssl;
  const int srcB0 = r0 * ldb + ssl, srcB1 = (128 + r0) * ldb + ssl;
  const int dstT = t * 8;

#pragma unroll
  for (int m = 0; m < 8; ++m)
#pragma unroll
    for (int n = 0; n < 4; ++n) acc[m][n] = (f32x4){0.f, 0.f, 0.f, 0.f};

#define ISSUE_UNIT(Ak, Bk, buf, h)                       \
  {                                                      \
    bf16_t* u_ = (buf) + (h)*UE;                         \
    const bf16_t* a_ = (Ak) + (h)*32;                    \
    const bf16_t* b_ = (Bk) + (h)*32;                    \
    async16(a_ + srcA0, u_ + dstT);                      \
    async16(a_ + srcA1, u_ + 4096 + dstT);               \
    async16(b_ + srcB0, u_ + 8192 + dstT);               \
    async16(b_ + srcB1, u_ + 12288 + dstT);              \
  }

  ISSUE_UNIT(A, B, lds, 0);
  ISSUE_UNIT(A, B, lds, 1);

  for (int tt = 0; tt < nt; ++tt) {
    bf16_t* cur = lds + (tt & 1) * BUFE;
    bf16_t* nxt = lds + ((tt + 1) & 1) * BUFE;
    const int kb = (tt + 1 < nt ? tt + 1 : 0) << 6;
    const bf16_t* An = A + kb;
    const bf16_t* Bn = B + kb;
#pragma unroll
    for (int h = 0; h < 2; ++h) {
      VMW4; BARR; FEN;
      const bf16_t* u = cur + h * UE;
      bf16x8 af[8], bv[4];
#pragma unroll
      for (int f = 0; f < 8; ++f) af[f] = *reinterpret_cast<const bf16x8*>(&u[aOff[f]]);
#pragma unroll
      for (int n = 0; n < 4; ++n) bv[n] = *reinterpret_cast<const bf16x8*>(&u[bOff[n]]);
      ISSUE_UNIT(An, Bn, nxt, h);
      __builtin_amdgcn_s_setprio(1);
#pragma unroll
      for (int mf = 0; mf < 8; ++mf)
#pragma unroll
        for (int nf = 0; nf < 4; ++nf)
          acc[mf][nf] = __builtin_amdgcn_mfma_f32_16x16x32_bf16(af[mf], bv[nf],
                                                                acc[mf][nf], 0, 0, 0);
      __builtin_amdgcn_s_setprio(0);
    }
  }
  VMW0; BARR; FEN;
#undef ISSUE_UNIT
}

// --- elementwise convert f32 -> bf16 ---------------------------------------
__global__ void k_cvt(const float4* __restrict__ in, bf16x4* __restrict__ out, int n4) {
  int i = blockIdx.x * blockDim.x + threadIdx.x;
  if (i < n4) {
    float4 v = in[i];
    bf16x4 o;
    o[0] = (bf16_t)v.x; o[1] = (bf16_t)v.y; o[2] = (bf16_t)v.z; o[3] = (bf16_t)v.w;
    out[i] = o;
  }
}

// --- tiled transpose + convert f32[R][C] -> bf16[C][R] ----------------------
__global__ void k_tconv(const float* __restrict__ in, bf16_t* __restrict__ out,
                        int R, int C) {
  __shared__ bf16_t tile[64][65];
  int bc = blockIdx.x, br = blockIdx.y;
  int t = threadIdx.x;
  int c = t & 63, r0 = t >> 6;
#pragma unroll
  for (int rr = 0; rr < 64; rr += 4) {
    int r = rr + r0;
    tile[r][c] = (bf16_t)in[(long)(br * 64 + r) * C + bc * 64 + c];
  }
  __syncthreads();
#pragma unroll
  for (int rr = 0; rr < 64; rr += 4) {
    int r = rr + r0;
    out[(long)(bc * 64 + r) * R + br * 64 + c] = tile[c][r];
  }
}

// --- GEMM1: QKVG = hsb @ Wt^T + bias; sigmoid z==3; z==2 -> Vt transposed ---
__global__ __launch_bounds__(512, 1) void k_gemm_qkvg(
    const bf16_t* __restrict__ hsb, const bf16_t* __restrict__ Wt4,
    const float* __restrict__ bq, const float* __restrict__ bk,
    const float* __restrict__ bv, const float* __restrict__ bg,
    bf16_t* __restrict__ out, bf16_t* __restrict__ Vt) {
  extern __shared__ bf16_t lds[];
  int i = blockIdx.x;
  int xcd = i & 7, j = i >> 3;
  int nb = xcd * 4 + (j & 3);  // 0..31
  int mb = j >> 2;             // 0..31
  f32x4 acc[8][4];
  core256(hsb + (long)mb * 256 * HID, HID, Wt4 + (long)nb * 256 * HID, HID,
          HID / 64, lds, acc);
  const int t = threadIdx.x, lane = t & 63, w = t >> 6;
  const int wm = w >> 2, wn = w & 3, lr = lane & 15, lg = lane >> 4;
  int z = nb >> 3;
  const float* bias = z == 0 ? bq : z == 1 ? bk : z == 2 ? bv : bg;
  int colT = (nb & 7) * 256;
  float b4[4];
#pragma unroll
  for (int nf = 0; nf < 4; ++nf) b4[nf] = bias[colT + wn * 64 + nf * 16 + lr];
#pragma unroll
  for (int rh = 0; rh < 2; ++rh) {
    if (wm == rh) {
#pragma unroll
      for (int mf = 0; mf < 8; ++mf)
#pragma unroll
        for (int reg = 0; reg < 4; ++reg) {
          int lrow = mf * 16 + lg * 4 + reg;
#pragma unroll
          for (int nf = 0; nf < 4; ++nf) {
            float v = acc[mf][nf][reg] + b4[nf];
            if (z == 3) v = 1.f / (1.f + __expf(-v));
            lds[lrow * SP + wn * 64 + nf * 16 + lr] = (bf16_t)v;
          }
        }
    }
    __syncthreads();
    if (z != 2) {
      bf16_t* O = out + (long)z * BS * DD + ((long)mb * 256 + rh * 128) * DD + colT;
#pragma unroll
      for (int it = 0; it < 8; ++it) {
        int s = it * 512 + t;
        int row = s >> 5, sg = s & 31;
        bf16x8 v = *reinterpret_cast<const bf16x8*>(&lds[row * SP + sg * 8]);
        *reinterpret_cast<bf16x8*>(&O[(long)row * DD + sg * 8]) = v;
      }
    } else {  // V: transpose into Vt[b][d][s]
      int bz = mb >> 4, smb = mb & 15;
      bf16_t* Vd = Vt + ((long)bz * DD + colT) * SEQ + smb * 256 + rh * 128;
#pragma unroll
      for (int it = 0; it < 8; ++it) {
        int idx = it * 512 + t;
        int d = idx >> 4, sg = idx & 15;
        bf16x8 v;
#pragma unroll
        for (int jj = 0; jj < 8; ++jj) v[jj] = lds[(sg * 8 + jj) * SP + d];
        *reinterpret_cast<bf16x8*>(&Vd[(long)d * SEQ + sg * 8]) = v;
      }
    }
    __syncthreads();
  }
}

// --- pair: 256x256 tiles (m,jt<=m); diag: per-chunk softmax fused -----------
__global__ __launch_bounds__(512, 1) void k_pair(const bf16_t* __restrict__ Q,
                                                 const bf16_t* __restrict__ Kb,
                                                 bf16_t* __restrict__ P) {
  extern __shared__ bf16_t lds[];
  int p = blockIdx.x, b = blockIdx.y;
  int m = 0, base = 0;
  while (base + m + 1 <= p) { base += m + 1; ++m; }
  int jt = p - base;  // 0..m
  f32x4 acc[8][4];
  core256(Q + ((long)b * SEQ + (long)m * 256) * DD, DD,
          Kb + ((long)b * SEQ + (long)jt * 256) * DD, DD, DD / 64, lds, acc);
  const int t = threadIdx.x, lane = t & 63, w = t >> 6;
  const int wm = w >> 2, wn = w & 3, lr = lane & 15, lg = lane >> 4;
  const bool diag = (jt == m);
  const float scale = 0.02209708691207961f;  // 1/sqrt(2048)
  bf16_t* Pt = P + ((long)b * SEQ + (long)m * 256) * (long)SEQ + (long)jt * 256;
#pragma unroll
  for (int rh = 0; rh < 2; ++rh) {
    if (wm == rh) {
#pragma unroll
      for (int mf = 0; mf < 8; ++mf)
#pragma unroll
        for (int reg = 0; reg < 4; ++reg) {
          int lrow = mf * 16 + lg * 4 + reg;
#pragma unroll
          for (int nf = 0; nf < 4; ++nf) {
            int col = wn * 64 + nf * 16 + lr;
            float v = acc[mf][nf][reg];
            if (diag) {
              int ch = col >> 7, c2 = col & 127;
              if (ch == rh) v = (c2 <= lrow) ? v * scale : -1e30f;  // logits
              else if (rh == 0) v = 0.f;   // future chunk
              // rh==1, ch==0: past chunk, raw
            }
            lds[lrow * SP + col] = (bf16_t)v;
          }
        }
    }
    __syncthreads();
    if (diag) {
      if (t < 128) {  // softmax row t over its chunk's 128-col segment
        bf16_t* rowp = lds + t * SP + rh * 128;
        float mx = -1e30f;
        for (int cc = 0; cc <= t; ++cc) mx = fmaxf(mx, (float)rowp[cc]);
        float ssum = 0.f;
        for (int cc = 0; cc <= t; ++cc) ssum += __expf((float)rowp[cc] - mx);
        float inv = 1.f / ssum;
        for (int cc = 0; cc < 128; ++cc) {
          float v = (cc <= t) ? __expf((float)rowp[cc] - mx) * inv : 0.f;
          rowp[cc] = (bf16_t)v;
        }
      }
      __syncthreads();
    }
    bf16_t* Po = Pt + (long)rh * 128 * SEQ;
#pragma unroll
    for (int it = 0; it < 8; ++it) {
      int s = it * 512 + t;
      int row = s >> 5, sg = s & 31;
      bf16x8 v = *reinterpret_cast<const bf16x8*>(&lds[row * SP + sg * 8]);
      *reinterpret_cast<bf16x8*>(&Po[(long)row * SEQ + sg * 8]) = v;
    }
    __syncthreads();
  }
}

// --- GEMM2: OutPre = (P @ V[0:K]) * gate; 256 blocks longest-first ----------
__global__ __launch_bounds__(512, 1) void k_gemm2(const bf16_t* __restrict__ P,
                                                  const bf16_t* __restrict__ Vt,
                                                  const bf16_t* __restrict__ G,
                                                  bf16_t* __restrict__ OutPre) {
  extern __shared__ bf16_t lds[];
  int bid = blockIdx.x;
  int ip = 15 - (bid >> 4);  // longest-first
  int nb = (bid >> 1) & 7, b2 = bid & 1;
  f32x4 acc[8][4];
  core256(P + ((long)b2 * SEQ + (long)ip * 256) * (long)SEQ, SEQ,
          Vt + (long)b2 * DD * SEQ + (long)nb * 256 * SEQ, SEQ, (ip + 1) * 4,
          lds, acc);
  const int t = threadIdx.x, lane = t & 63, w = t >> 6;
  const int wm = w >> 2, wn = w & 3, lr = lane & 15, lg = lane >> 4;
  long rowb = (long)b2 * SEQ + (long)ip * 256;
  int colT = nb * 256;
#pragma unroll
  for (int rh = 0; rh < 2; ++rh) {
    if (wm == rh) {
#pragma unroll
      for (int mf = 0; mf < 8; ++mf)
#pragma unroll
        for (int reg = 0; reg < 4; ++reg) {
          int lrow = mf * 16 + lg * 4 + reg;
#pragma unroll
          for (int nf = 0; nf < 4; ++nf)
            lds[lrow * SP + wn * 64 + nf * 16 + lr] = (bf16_t)acc[mf][nf][reg];
        }
    }
    __syncthreads();
    bf16_t* O = OutPre + (rowb + rh * 128) * DD + colT;
    const bf16_t* Gp = G + (rowb + rh * 128) * DD + colT;
#pragma unroll
    for (int it = 0; it < 8; ++it) {
      int s = it * 512 + t;
      int row = s >> 5, sg = s & 31;
      bf16x8 v = *reinterpret_cast<const bf16x8*>(&lds[row * SP + sg * 8]);
      bf16x8 gv = *reinterpret_cast<const bf16x8*>(&Gp[(long)row * DD + sg * 8]);
      bf16x8 o;
#pragma unroll
      for (int jj = 0; jj < 8; ++jj) o[jj] = (bf16_t)((float)v[jj] * (float)gv[jj]);
      *reinterpret_cast<bf16x8*>(&O[(long)row * DD + sg * 8]) = o;
    }
    __syncthreads();
  }
}

// --- GEMM3: out = OutPre @ Wo + bo (f32 direct) -----------------------------
__global__ __launch_bounds__(512, 1) void k_gemm3(const bf16_t* __restrict__ OutPre,
                                                  const bf16_t* __restrict__ Wot,
                                                  const float* __restrict__ bo,
                                                  float* __restrict__ out) {
  extern __shared__ bf16_t lds[];
  int mb = blockIdx.x >> 2, nb = blockIdx.x & 3;
  f32x4 acc[8][4];
  core256(OutPre + (long)mb * 256 * DD, DD, Wot + (long)nb * 256 * DD, DD,
          DD / 64, lds, acc);
  const int t = threadIdx.x, lane = t & 63, w = t >> 6;
  const int wm = w >> 2, wn = w & 3, lr = lane & 15, lg = lane >> 4;
  int colbase = nb * 256 + wn * 64;
  float b4[4];
#pragma unroll
  for (int nf = 0; nf < 4; ++nf) b4[nf] = bo[colbase + nf * 16 + lr];
#pragma unroll
  for (int mf = 0; mf < 8; ++mf)
#pragma unroll
    for (int reg = 0; reg < 4; ++reg) {
      long row = mb * 256 + wm * 128 + mf * 16 + lg * 4 + reg;
#pragma unroll
      for (int nf = 0; nf < 4; ++nf)
        out[row * HID + colbase + nf * 16 + lr] = acc[mf][nf][reg] + b4[nf];
    }
}

extern "C" void kernel_launch(void* const* d_in, const int* in_sizes, int n_in,
                              void* d_out, int out_size, void* d_ws, size_t ws_size,
                              hipStream_t stream) {
  const float* hs = (const float*)d_in[0];
  const float* Wq = (const float*)d_in[1];
  const float* bq = (const float*)d_in[2];
  const float* Wk = (const float*)d_in[3];
  const float* bk = (const float*)d_in[4];
  const float* Wv = (const float*)d_in[5];
  const float* bv = (const float*)d_in[6];
  const float* Wg = (const float*)d_in[7];
  const float* bg = (const float*)d_in[8];
  const float* Wo = (const float*)d_in[9];
  const float* bo = (const float*)d_in[10];
  float* out = (float*)d_out;

  char* ws = (char*)d_ws;
  const size_t MB = 1024 * 1024;
  bf16_t* P = (bf16_t*)(ws);            // [2][4096][4096] bf16, 64MB
  bf16_t* hsb = (bf16_t*)(ws);          // aliases P (dead before pair)
  bf16_t* Wt4 = (bf16_t*)(ws + 16 * MB);
  bf16_t* Wot = (bf16_t*)(ws + 64 * MB);
  bf16_t* QKVG = (bf16_t*)(ws + 68 * MB);
  bf16_t* Vt = (bf16_t*)(ws + 196 * MB);

  bf16_t* Qb = QKVG;
  bf16_t* Kbuf = QKVG + (long)BS * DD;
  bf16_t* Vbuf = QKVG + 2l * BS * DD;  // unused by V (V -> Vt directly)
  bf16_t* Gbuf = QKVG + 3l * BS * DD;
  bf16_t* OutPre = Vbuf;

  hipFuncSetAttribute((const void*)k_gemm_qkvg,
                      hipFuncAttributeMaxDynamicSharedMemorySize, LDS_CORE);
  hipFuncSetAttribute((const void*)k_pair,
                      hipFuncAttributeMaxDynamicSharedMemorySize, LDS_CORE);
  hipFuncSetAttribute((const void*)k_gemm2,
                      hipFuncAttributeMaxDynamicSharedMemorySize, LDS_CORE);
  hipFuncSetAttribute((const void*)k_gemm3,
                      hipFuncAttributeMaxDynamicSharedMemorySize, LDS_CORE);

  // 1. conversions
  k_cvt<<<(BS * HID / 4 + 255) / 256, 256, 0, stream>>>((const float4*)hs,
                                                        (bf16x4*)hsb, BS * HID / 4);
  k_tconv<<<dim3(DD / 64, HID / 64), 256, 0, stream>>>(Wq, Wt4 + 0l * DD * HID, HID, DD);
  k_tconv<<<dim3(DD / 64, HID / 64), 256, 0, stream>>>(Wk, Wt4 + 1l * DD * HID, HID, DD);
  k_tconv<<<dim3(DD / 64, HID / 64), 256, 0, stream>>>(Wv, Wt4 + 2l * DD * HID, HID, DD);
  k_tconv<<<dim3(DD / 64, HID / 64), 256, 0, stream>>>(Wg, Wt4 + 3l * DD * HID, HID, DD);
  k_tconv<<<dim3(HID / 64, DD / 64), 256, 0, stream>>>(Wo, Wot, DD, HID);

  // 2. QKVG projection (1024 blocks; per-XCD 4-nb W slabs; V fused -> Vt)
  k_gemm_qkvg<<<1024, 512, LDS_CORE, stream>>>(hsb, Wt4, bq, bk, bv, bg, QKVG, Vt);

  // 3. pairwise scores + fused diag softmax (272 tiles of 256x256)
  k_pair<<<dim3(136, 2), 512, LDS_CORE, stream>>>(Qb, Kbuf, P);

  // 4. PV + gate (256 blocks, longest-first)
  k_gemm2<<<256, 512, LDS_CORE, stream>>>(P, Vt, Gbuf, OutPre);

  // 5. output projection (128 blocks)
  k_gemm3<<<128, 512, LDS_CORE, stream>>>(OutPre, Wot, bo, out);
}

// Round 10
// 492.408 us; speedup vs baseline: 1.0673x; 1.0673x over previous
//
#include <hip/hip_runtime.h>
#include <hip/hip_bf16.h>
#include <math.h>

// ---------------------------------------------------------------------------
// ChunkGatedAttentionUnit: B=2, S=4096, H=1024, D=2048, CHUNK=128, nC=32
// Round 10: identical to round 9 (infra failure, no data). 8-phase core256 on
// the proven conflict-free LDS layout ([row][64] bf16, slot ^= row&7).
// 4 phases/K-tile x 16 MFMA, counted vmcnt(2) at ph0/ph1 only, setprio.
// ---------------------------------------------------------------------------

typedef __bf16 bf16_t;
typedef __bf16 bf16x8 __attribute__((ext_vector_type(8)));
typedef __bf16 bf16x4 __attribute__((ext_vector_type(4)));
typedef float f32x4 __attribute__((ext_vector_type(4)));

#define NB_ 2
#define SEQ 4096
#define HID 1024
#define DD 2048
#define BS 8192
#define LDS_CORE 131072
#define SP 264

__device__ __forceinline__ void async16(const void* g, void* l) {
  __builtin_amdgcn_global_load_lds(
      (const __attribute__((address_space(1))) void*)g,
      (__attribute__((address_space(3))) void*)l, 16, 0, 0);
}

#define VMW(n) asm volatile("s_waitcnt vmcnt(" #n ")" ::: "memory")
#define BARR __builtin_amdgcn_s_barrier()
#define FEN asm volatile("" ::: "memory")
#define LDV(p) (*reinterpret_cast<const bf16x8*>(p))

// C[256,256] = A[256,K] @ B[256,K]^T, BK=64. 8 waves (2M x 4N), per-wave
// 128x64, acc[8][4]. LDS buffer (per K-tile): A[256][64] then B[256][64],
// 8 x 16B slots/row, physical slot = logical ^ (row&7)  (conflict-free per
// 8-lane beat; inverse folded into global src). 4 phases/K-tile:
//   ph0 (m0-3,kk0): vmcnt(2) [B0-3,A0,A2 landed]; reads 8; issue B0',B1'
//   ph1 (m4-7,kk0): vmcnt(2) [A1,A3 landed]; reads 4 + 8 ahead; issue B2',B3'
//   ph2 (m0-3,kk1): reads 4 ahead; issue A0',A2'
//   ph3 (m4-7,kk1): issue A1',A3'
__device__ __forceinline__ void core256(const bf16_t* __restrict__ A, int lda,
                                        const bf16_t* __restrict__ B, int ldb, int nt,
                                        bf16_t* lds, f32x4 (&acc)[8][4]) {
  const int t = threadIdx.x, lane = t & 63, w = t >> 6;
  const int wm = w >> 2, wn = w & 3;
  const int lr = lane & 15, lg = lane >> 4;
  const int x7 = lr & 7;
  const int s0 = (lg ^ x7) * 8;        // kk0 slot (elems)
  const int s1 = ((4 + lg) ^ x7) * 8;  // kk1 slot
  int arL[4], arH[4], brr[4];
#pragma unroll
  for (int f = 0; f < 4; ++f) {
    arL[f] = (wm * 128 + f * 16 + lr) * 64;
    arH[f] = arL[f] + 64 * 64;
    brr[f] = 16384 + (wn * 64 + f * 16 + lr) * 64;
  }
  const int slog = ((t & 7) ^ ((t >> 3) & 7)) * 8;
  const int tr = t >> 3;
  int srcA[4], srcB[4];
#pragma unroll
  for (int q = 0; q < 4; ++q) {
    srcA[q] = (q * 64 + tr) * lda + slog;
    srcB[q] = (q * 64 + tr) * ldb + slog;
  }
  const int dstT = t * 8;
#pragma unroll
  for (int m = 0; m < 8; ++m)
#pragma unroll
    for (int n = 0; n < 4; ++n) acc[m][n] = (f32x4){0.f, 0.f, 0.f, 0.f};

  // prologue: tile 0, canonical order B0,B1,B2,B3,A0,A2,A1,A3
  async16(B + srcB[0], lds + 16384 + dstT);
  async16(B + srcB[1], lds + 16384 + 4096 + dstT);
  async16(B + srcB[2], lds + 16384 + 8192 + dstT);
  async16(B + srcB[3], lds + 16384 + 12288 + dstT);
  async16(A + srcA[0], lds + dstT);
  async16(A + srcA[2], lds + 8192 + dstT);
  async16(A + srcA[1], lds + 4096 + dstT);
  async16(A + srcA[3], lds + 12288 + dstT);

  for (int tt = 0; tt < nt; ++tt) {
    bf16_t* cur = lds + (tt & 1) * 32768;
    bf16_t* nxt = lds + ((tt + 1) & 1) * 32768;
    const int kb = (tt + 1 < nt ? tt + 1 : 0) << 6;
    const bf16_t* An = A + kb;
    const bf16_t* Bn = B + kb;
    bf16x8 afl0[4], afh0[4], afl1[4], afh1[4], bv0[4], bv1[4];
    // ---- ph0: (m0-3, kk0) ----
    VMW(2); FEN;
    BARR; FEN;
#pragma unroll
    for (int f = 0; f < 4; ++f) afl0[f] = LDV(&cur[arL[f] + s0]);
#pragma unroll
    for (int n = 0; n < 4; ++n) bv0[n] = LDV(&cur[brr[n] + s0]);
    async16(Bn + srcB[0], nxt + 16384 + dstT);
    async16(Bn + srcB[1], nxt + 16384 + 4096 + dstT);
    __builtin_amdgcn_s_setprio(1);
#pragma unroll
    for (int mf = 0; mf < 4; ++mf)
#pragma unroll
      for (int nf = 0; nf < 4; ++nf)
        acc[mf][nf] =
            __builtin_amdgcn_mfma_f32_16x16x32_bf16(afl0[mf], bv0[nf], acc[mf][nf], 0, 0, 0);
    __builtin_amdgcn_s_setprio(0);
    BARR; FEN;
    // ---- ph1: (m4-7, kk0); read ph2's frags ahead (rows confirmed at ph0) --
    VMW(2); FEN;
    BARR; FEN;
#pragma unroll
    for (int f = 0; f < 4; ++f) afh0[f] = LDV(&cur[arH[f] + s0]);
#pragma unroll
    for (int f = 0; f < 4; ++f) afl1[f] = LDV(&cur[arL[f] + s1]);
#pragma unroll
    for (int n = 0; n < 4; ++n) bv1[n] = LDV(&cur[brr[n] + s1]);
    async16(Bn + srcB[2], nxt + 16384 + 8192 + dstT);
    async16(Bn + srcB[3], nxt + 16384 + 12288 + dstT);
    __builtin_amdgcn_s_setprio(1);
#pragma unroll
    for (int mf = 0; mf < 4; ++mf)
#pragma unroll
      for (int nf = 0; nf < 4; ++nf)
        acc[4 + mf][nf] =
            __builtin_amdgcn_mfma_f32_16x16x32_bf16(afh0[mf], bv0[nf], acc[4 + mf][nf], 0, 0, 0);
    __builtin_amdgcn_s_setprio(0);
    BARR; FEN;
    // ---- ph2: (m0-3, kk1) ----
#pragma unroll
    for (int f = 0; f < 4; ++f) afh1[f] = LDV(&cur[arH[f] + s1]);
    async16(An + srcA[0], nxt + dstT);
    async16(An + srcA[2], nxt + 8192 + dstT);
    __builtin_amdgcn_s_setprio(1);
#pragma unroll
    for (int mf = 0; mf < 4; ++mf)
#pragma unroll
      for (int nf = 0; nf < 4; ++nf)
        acc[mf][nf] =
            __builtin_amdgcn_mfma_f32_16x16x32_bf16(afl1[mf], bv1[nf], acc[mf][nf], 0, 0, 0);
    __builtin_amdgcn_s_setprio(0);
    BARR; FEN;
    // ---- ph3: (m4-7, kk1) ----
    async16(An + srcA[1], nxt + 4096 + dstT);
    async16(An + srcA[3], nxt + 12288 + dstT);
    __builtin_amdgcn_s_setprio(1);
#pragma unroll
    for (int mf = 0; mf < 4; ++mf)
#pragma unroll
      for (int nf = 0; nf < 4; ++nf)
        acc[4 + mf][nf] =
            __builtin_amdgcn_mfma_f32_16x16x32_bf16(afh1[mf], bv1[nf], acc[4 + mf][nf], 0, 0, 0);
    __builtin_amdgcn_s_setprio(0);
    BARR; FEN;
  }
  VMW(0); FEN;
  BARR; FEN;
}

// --- elementwise convert f32 -> bf16 ---------------------------------------
__global__ void k_cvt(const float4* __restrict__ in, bf16x4* __restrict__ out, int n4) {
  int i = blockIdx.x * blockDim.x + threadIdx.x;
  if (i < n4) {
    float4 v = in[i];
    bf16x4 o;
    o[0] = (bf16_t)v.x; o[1] = (bf16_t)v.y; o[2] = (bf16_t)v.z; o[3] = (bf16_t)v.w;
    out[i] = o;
  }
}

// --- tiled transpose + convert f32[R][C] -> bf16[C][R] ----------------------
__global__ void k_tconv(const float* __restrict__ in, bf16_t* __restrict__ out,
                        int R, int C) {
  __shared__ bf16_t tile[64][65];
  int bc = blockIdx.x, br = blockIdx.y;
  int t = threadIdx.x;
  int c = t & 63, r0 = t >> 6;
#pragma unroll
  for (int rr = 0; rr < 64; rr += 4) {
    int r = rr + r0;
    tile[r][c] = (bf16_t)in[(long)(br * 64 + r) * C + bc * 64 + c];
  }
  __syncthreads();
#pragma unroll
  for (int rr = 0; rr < 64; rr += 4) {
    int r = rr + r0;
    out[(long)(bc * 64 + r) * R + br * 64 + c] = tile[c][r];
  }
}

// --- GEMM1: QKVG = hsb @ Wt^T + bias; sigmoid z==3; z==2 -> Vt transposed ---
__global__ __launch_bounds__(512, 2) void k_gemm_qkvg(
    const bf16_t* __restrict__ hsb, const bf16_t* __restrict__ Wt4,
    const float* __restrict__ bq, const float* __restrict__ bk,
    const float* __restrict__ bv, const float* __restrict__ bg,
    bf16_t* __restrict__ out, bf16_t* __restrict__ Vt) {
  extern __shared__ bf16_t lds[];
  int i = blockIdx.x;
  int xcd = i & 7, j = i >> 3;
  int nb = xcd * 4 + (j & 3);  // 0..31
  int mb = j >> 2;             // 0..31
  f32x4 acc[8][4];
  core256(hsb + (long)mb * 256 * HID, HID, Wt4 + (long)nb * 256 * HID, HID,
          HID / 64, lds, acc);
  const int t = threadIdx.x, lane = t & 63, w = t >> 6;
  const int wm = w >> 2, wn = w & 3, lr = lane & 15, lg = lane >> 4;
  int z = nb >> 3;
  const float* bias = z == 0 ? bq : z == 1 ? bk : z == 2 ? bv : bg;
  int colT = (nb & 7) * 256;
  float b4[4];
#pragma unroll
  for (int nf = 0; nf < 4; ++nf) b4[nf] = bias[colT + wn * 64 + nf * 16 + lr];
#pragma unroll
  for (int rh = 0; rh < 2; ++rh) {
    if (wm == rh) {
#pragma unroll
      for (int mf = 0; mf < 8; ++mf)
#pragma unroll
        for (int reg = 0; reg < 4; ++reg) {
          int lrow = mf * 16 + lg * 4 + reg;
#pragma unroll
          for (int nf = 0; nf < 4; ++nf) {
            float v = acc[mf][nf][reg] + b4[nf];
            if (z == 3) v = 1.f / (1.f + __expf(-v));
            lds[lrow * SP + wn * 64 + nf * 16 + lr] = (bf16_t)v;
          }
        }
    }
    __syncthreads();
    if (z != 2) {
      bf16_t* O = out + (long)z * BS * DD + ((long)mb * 256 + rh * 128) * DD + colT;
#pragma unroll
      for (int it = 0; it < 8; ++it) {
        int s = it * 512 + t;
        int row = s >> 5, sg = s & 31;
        bf16x8 v = *reinterpret_cast<const bf16x8*>(&lds[row * SP + sg * 8]);
        *reinterpret_cast<bf16x8*>(&O[(long)row * DD + sg * 8]) = v;
      }
    } else {  // V: transpose into Vt[b][d][s]
      int bz = mb >> 4, smb = mb & 15;
      bf16_t* Vd = Vt + ((long)bz * DD + colT) * SEQ + smb * 256 + rh * 128;
#pragma unroll
      for (int it = 0; it < 8; ++it) {
        int idx = it * 512 + t;
        int d = idx >> 4, sg = idx & 15;
        bf16x8 v;
#pragma unroll
        for (int jj = 0; jj < 8; ++jj) v[jj] = lds[(sg * 8 + jj) * SP + d];
        *reinterpret_cast<bf16x8*>(&Vd[(long)d * SEQ + sg * 8]) = v;
      }
    }
    __syncthreads();
  }
}

// --- pair: 256x256 tiles (m,jt<=m); diag: per-chunk softmax fused -----------
__global__ __launch_bounds__(512, 2) void k_pair(const bf16_t* __restrict__ Q,
                                                 const bf16_t* __restrict__ Kb,
                                                 bf16_t* __restrict__ P) {
  extern __shared__ bf16_t lds[];
  int p = blockIdx.x, b = blockIdx.y;
  int m = 0, base = 0;
  while (base + m + 1 <= p) { base += m + 1; ++m; }
  int jt = p - base;  // 0..m
  f32x4 acc[8][4];
  core256(Q + ((long)b * SEQ + (long)m * 256) * DD, DD,
          Kb + ((long)b * SEQ + (long)jt * 256) * DD, DD, DD / 64, lds, acc);
  const int t = threadIdx.x, lane = t & 63, w = t >> 6;
  const int wm = w >> 2, wn = w & 3, lr = lane & 15, lg = lane >> 4;
  const bool diag = (jt == m);
  const float scale = 0.02209708691207961f;  // 1/sqrt(2048)
  bf16_t* Pt = P + ((long)b * SEQ + (long)m * 256) * (long)SEQ + (long)jt * 256;
#pragma unroll
  for (int rh = 0; rh < 2; ++rh) {
    if (wm == rh) {
#pragma unroll
      for (int mf = 0; mf < 8; ++mf)
#pragma unroll
        for (int reg = 0; reg < 4; ++reg) {
          int lrow = mf * 16 + lg * 4 + reg;
#pragma unroll
          for (int nf = 0; nf < 4; ++nf) {
            int col = wn * 64 + nf * 16 + lr;
            float v = acc[mf][nf][reg];
            if (diag) {
              int ch = col >> 7, c2 = col & 127;
              if (ch == rh) v = (c2 <= lrow) ? v * scale : -1e30f;  // logits
              else if (rh == 0) v = 0.f;   // future chunk
            }
            lds[lrow * SP + col] = (bf16_t)v;
          }
        }
    }
    __syncthreads();
    if (diag) {
      if (t < 128) {  // softmax row t over its chunk's 128-col segment
        bf16_t* rowp = lds + t * SP + rh * 128;
        float mx = -1e30f;
        for (int cc = 0; cc <= t; ++cc) mx = fmaxf(mx, (float)rowp[cc]);
        float ssum = 0.f;
        for (int cc = 0; cc <= t; ++cc) ssum += __expf((float)rowp[cc] - mx);
        float inv = 1.f / ssum;
        for (int cc = 0; cc < 128; ++cc) {
          float v = (cc <= t) ? __expf((float)rowp[cc] - mx) * inv : 0.f;
          rowp[cc] = (bf16_t)v;
        }
      }
      __syncthreads();
    }
    bf16_t* Po = Pt + (long)rh * 128 * SEQ;
#pragma unroll
    for (int it = 0; it < 8; ++it) {
      int s = it * 512 + t;
      int row = s >> 5, sg = s & 31;
      bf16x8 v = *reinterpret_cast<const bf16x8*>(&lds[row * SP + sg * 8]);
      *reinterpret_cast<bf16x8*>(&Po[(long)row * SEQ + sg * 8]) = v;
    }
    __syncthreads();
  }
}

// --- GEMM2: OutPre = (P @ V[0:K]) * gate; 256 blocks ------------------------
__global__ __launch_bounds__(512, 2) void k_gemm2(const bf16_t* __restrict__ P,
                                                  const bf16_t* __restrict__ Vt,
                                                  const bf16_t* __restrict__ G,
                                                  bf16_t* __restrict__ OutPre) {
  extern __shared__ bf16_t lds[];
  int bid = blockIdx.x;
  int ip = 15 - (bid >> 4);  // longest-first
  int nb = (bid >> 1) & 7, b2 = bid & 1;
  f32x4 acc[8][4];
  core256(P + ((long)b2 * SEQ + (long)ip * 256) * (long)SEQ, SEQ,
          Vt + (long)b2 * DD * SEQ + (long)nb * 256 * SEQ, SEQ, (ip + 1) * 4,
          lds, acc);
  const int t = threadIdx.x, lane = t & 63, w = t >> 6;
  const int wm = w >> 2, wn = w & 3, lr = lane & 15, lg = lane >> 4;
  long rowb = (long)b2 * SEQ + (long)ip * 256;
  int colT = nb * 256;
#pragma unroll
  for (int rh = 0; rh < 2; ++rh) {
    if (wm == rh) {
#pragma unroll
      for (int mf = 0; mf < 8; ++mf)
#pragma unroll
        for (int reg = 0; reg < 4; ++reg) {
          int lrow = mf * 16 + lg * 4 + reg;
#pragma unroll
          for (int nf = 0; nf < 4; ++nf)
            lds[lrow * SP + wn * 64 + nf * 16 + lr] = (bf16_t)acc[mf][nf][reg];
        }
    }
    __syncthreads();
    bf16_t* O = OutPre + (rowb + rh * 128) * DD + colT;
    const bf16_t* Gp = G + (rowb + rh * 128) * DD + colT;
#pragma unroll
    for (int it = 0; it < 8; ++it) {
      int s = it * 512 + t;
      int row = s >> 5, sg = s & 31;
      bf16x8 v = *reinterpret_cast<const bf16x8*>(&lds[row * SP + sg * 8]);
      bf16x8 gv = *reinterpret_cast<const bf16x8*>(&Gp[(long)row * DD + sg * 8]);
      bf16x8 o;
#pragma unroll
      for (int jj = 0; jj < 8; ++jj) o[jj] = (bf16_t)((float)v[jj] * (float)gv[jj]);
      *reinterpret_cast<bf16x8*>(&O[(long)row * DD + sg * 8]) = o;
    }
    __syncthreads();
  }
}

// --- GEMM3: out = OutPre @ Wo + bo (f32 direct) -----------------------------
__global__ __launch_bounds__(512, 2) void k_gemm3(const bf16_t* __restrict__ OutPre,
                                                  const bf16_t* __restrict__ Wot,
                                                  const float* __restrict__ bo,
                                                  float* __restrict__ out) {
  extern __shared__ bf16_t lds[];
  int mb = blockIdx.x >> 2, nb = blockIdx.x & 3;
  f32x4 acc[8][4];
  core256(OutPre + (long)mb * 256 * DD, DD, Wot + (long)nb * 256 * DD, DD,
          DD / 64, lds, acc);
  const int t = threadIdx.x, lane = t & 63, w = t >> 6;
  const int wm = w >> 2, wn = w & 3, lr = lane & 15, lg = lane >> 4;
  int colbase = nb * 256 + wn * 64;
  float b4[4];
#pragma unroll
  for (int nf = 0; nf < 4; ++nf) b4[nf] = bo[colbase + nf * 16 + lr];
#pragma unroll
  for (int mf = 0; mf < 8; ++mf)
#pragma unroll
    for (int reg = 0; reg < 4; ++reg) {
      long row = mb * 256 + wm * 128 + mf * 16 + lg * 4 + reg;
#pragma unroll
      for (int nf = 0; nf < 4; ++nf)
        out[row * HID + colbase + nf * 16 + lr] = acc[mf][nf][reg] + b4[nf];
    }
}

extern "C" void kernel_launch(void* const* d_in, const int* in_sizes, int n_in,
                              void* d_out, int out_size, void* d_ws, size_t ws_size,
                              hipStream_t stream) {
  const float* hs = (const float*)d_in[0];
  const float* Wq = (const float*)d_in[1];
  const float* bq = (const float*)d_in[2];
  const float* Wk = (const float*)d_in[3];
  const float* bk = (const float*)d_in[4];
  const float* Wv = (const float*)d_in[5];
  const float* bv = (const float*)d_in[6];
  const float* Wg = (const float*)d_in[7];
  const float* bg = (const float*)d_in[8];
  const float* Wo = (const float*)d_in[9];
  const float* bo = (const float*)d_in[10];
  float* out = (float*)d_out;

  char* ws = (char*)d_ws;
  const size_t MB = 1024 * 1024;
  bf16_t* P = (bf16_t*)(ws);            // [2][4096][4096] bf16, 64MB
  bf16_t* hsb = (bf16_t*)(ws);          // aliases P (dead before pair)
  bf16_t* Wt4 = (bf16_t*)(ws + 16 * MB);
  bf16_t* Wot = (bf16_t*)(ws + 64 * MB);
  bf16_t* QKVG = (bf16_t*)(ws + 68 * MB);
  bf16_t* Vt = (bf16_t*)(ws + 196 * MB);

  bf16_t* Qb = QKVG;
  bf16_t* Kbuf = QKVG + (long)BS * DD;
  bf16_t* Vbuf = QKVG + 2l * BS * DD;  // V row-major unused (V -> Vt directly)
  bf16_t* Gbuf = QKVG + 3l * BS * DD;
  bf16_t* OutPre = Vbuf;

  hipFuncSetAttribute((const void*)k_gemm_qkvg,
                      hipFuncAttributeMaxDynamicSharedMemorySize, LDS_CORE);
  hipFuncSetAttribute((const void*)k_pair,
                      hipFuncAttributeMaxDynamicSharedMemorySize, LDS_CORE);
  hipFuncSetAttribute((const void*)k_gemm2,
                      hipFuncAttributeMaxDynamicSharedMemorySize, LDS_CORE);
  hipFuncSetAttribute((const void*)k_gemm3,
                      hipFuncAttributeMaxDynamicSharedMemorySize, LDS_CORE);

  // 1. conversions
  k_cvt<<<(BS * HID / 4 + 255) / 256, 256, 0, stream>>>((const float4*)hs,
                                                        (bf16x4*)hsb, BS * HID / 4);
  k_tconv<<<dim3(DD / 64, HID / 64), 256, 0, stream>>>(Wq, Wt4 + 0l * DD * HID, HID, DD);
  k_tconv<<<dim3(DD / 64, HID / 64), 256, 0, stream>>>(Wk, Wt4 + 1l * DD * HID, HID, DD);
  k_tconv<<<dim3(DD / 64, HID / 64), 256, 0, stream>>>(Wv, Wt4 + 2l * DD * HID, HID, DD);
  k_tconv<<<dim3(DD / 64, HID / 64), 256, 0, stream>>>(Wg, Wt4 + 3l * DD * HID, HID, DD);
  k_tconv<<<dim3(HID / 64, DD / 64), 256, 0, stream>>>(Wo, Wot, DD, HID);

  // 2. QKVG projection (1024 blocks; per-XCD W slabs; V fused -> Vt)
  k_gemm_qkvg<<<1024, 512, LDS_CORE, stream>>>(hsb, Wt4, bq, bk, bv, bg, QKVG, Vt);

  // 3. pairwise scores + fused diag softmax (272 tiles of 256x256)
  k_pair<<<dim3(136, 2), 512, LDS_CORE, stream>>>(Qb, Kbuf, P);

  // 4. PV + gate (256 blocks, longest-first)
  k_gemm2<<<256, 512, LDS_CORE, stream>>>(P, Vt, Gbuf, OutPre);

  // 5. output projection (128 blocks)
  k_gemm3<<<128, 512, LDS_CORE, stream>>>(OutPre, Wot, bo, out);
}

// Round 11
// 422.458 us; speedup vs baseline: 1.2440x; 1.1656x over previous
//
#include <hip/hip_runtime.h>
#include <hip/hip_bf16.h>
#include <math.h>

// ---------------------------------------------------------------------------
// ChunkGatedAttentionUnit: B=2, S=4096, H=1024, D=2048, CHUNK=128, nC=32
// Round 11: bank best-measured components.
//   - qkvg: R7's coreK32<4,2> (2 blk/CU, fused V->Vt) with the V-transpose
//     epilogue re-staged TRANSPOSED in LDS (fixes 16-lane bank conflict).
//   - pair/gemm2/gemm3: R3's core128 2-sync kernels (best measured "rest").
//   - k_tbf16 deleted (V never round-trips row-major).
// ---------------------------------------------------------------------------

typedef __bf16 bf16_t;
typedef __bf16 bf16x8 __attribute__((ext_vector_type(8)));
typedef __bf16 bf16x4 __attribute__((ext_vector_type(4)));
typedef float f32x4 __attribute__((ext_vector_type(4)));

#define NB_ 2
#define SEQ 4096
#define HID 1024
#define DD 2048
#define BS 8192
#define LDS_128 98304   // core128 dbuf: 2 x (16KB A + 32KB B)
#define LDS_QKVG 69632  // max(coreK32<4,2> dbuf 49152, staging 256*136*2)

__device__ __forceinline__ void async16(const void* g, void* l) {
  __builtin_amdgcn_global_load_lds(
      (const __attribute__((address_space(1))) void*)g,
      (__attribute__((address_space(3))) void*)l, 16, 0, 0);
}

#define VMW(n) asm volatile("s_waitcnt vmcnt(" #n ")" ::: "memory")
#define VMW0 asm volatile("s_waitcnt vmcnt(0)" ::: "memory")
#define BARR __builtin_amdgcn_s_barrier()
#define FEN asm volatile("" ::: "memory")

// ===== R3's BM=128 x BN=256 core (2 counted-vmcnt syncs per K-tile) =========
template <int MFH>
__device__ __forceinline__ void readA8(const bf16_t* bufA, int aBase, int s0, int s1,
                                       bf16x8 (&af)[4][2]) {
#pragma unroll
  for (int mm = 0; mm < 4; ++mm) {
    int p = aBase + MFH * 8192 + mm * 1024;
    af[mm][0] = *reinterpret_cast<const bf16x8*>(&bufA[p + s0]);
    af[mm][1] = *reinterpret_cast<const bf16x8*>(&bufA[p + s1]);
  }
}
template <int NFH>
__device__ __forceinline__ void readB4(const bf16_t* bufB, int bBase, int s0, int s1,
                                       bf16x8 (&bv)[2][2]) {
#pragma unroll
  for (int nn = 0; nn < 2; ++nn) {
    int p = bBase + NFH * 8192 + nn * 1024;
    bv[nn][0] = *reinterpret_cast<const bf16x8*>(&bufB[p + s0]);
    bv[nn][1] = *reinterpret_cast<const bf16x8*>(&bufB[p + s1]);
  }
}
template <int MROWS, int MQ, int NQ>
__device__ __forceinline__ void mfmaQ(const bf16x8 (&af)[4][2], const bf16x8 (&bv)[2][2],
                                      f32x4 (&acc)[MROWS][4]) {
  __builtin_amdgcn_s_setprio(1);
#pragma unroll
  for (int kki = 0; kki < 2; ++kki)
#pragma unroll
    for (int mm = 0; mm < 4; ++mm)
#pragma unroll
      for (int nn = 0; nn < 2; ++nn)
        acc[MQ * 4 + mm][NQ * 2 + nn] = __builtin_amdgcn_mfma_f32_16x16x32_bf16(
            af[mm][kki], bv[nn][kki], acc[MQ * 4 + mm][NQ * 2 + nn], 0, 0, 0);
  __builtin_amdgcn_s_setprio(0);
}

__device__ __forceinline__ void core128(const bf16_t* __restrict__ A, int lda,
                                        const bf16_t* __restrict__ B, int ldb, int nt,
                                        bf16_t* lds, f32x4 (&acc)[4][4]) {
  const int t = threadIdx.x;
  const int lane = t & 63, w = t >> 6;
  const int wm = w >> 2, wn = w & 3;
  const int lr = lane & 15, lg = lane >> 4;
  const int xm = lr & 7;
  const int aBase = (wm * 64 + lr) * 64;
  const int bBase = (wn * 32 + lr) * 64;
  const int s0 = (lg ^ xm) * 8, s1 = ((4 + lg) ^ xm) * 8;
  const int slog = ((t & 7) ^ ((t >> 3) & 7)) * 8;
  int srcA[2], srcB[4];
#pragma unroll
  for (int blk = 0; blk < 2; ++blk) srcA[blk] = (blk * 64 + (t >> 3)) * lda + slog;
#pragma unroll
  for (int blk = 0; blk < 4; ++blk) {
    int prB = (blk << 6) + (t >> 3);
    int rB = (((prB >> 5) & 3) << 6) + ((prB >> 7) << 5) + (prB & 31);
    srcB[blk] = rB * ldb + slog;
  }
  const int dstT = t * 8;
#pragma unroll
  for (int m = 0; m < 4; ++m)
#pragma unroll
    for (int n = 0; n < 4; ++n) acc[m][n] = (f32x4){0.f, 0.f, 0.f, 0.f};

  {  // prologue: order A0,A1,B0,B1,B2,B3
    bf16_t* nA = lds;
    bf16_t* nB = lds + 8192;
    async16(A + srcA[0], nA + dstT);
    async16(A + srcA[1], nA + 4096 + dstT);
    async16(B + srcB[0], nB + dstT);
    async16(B + srcB[1], nB + 4096 + dstT);
    async16(B + srcB[2], nB + 8192 + dstT);
    async16(B + srcB[3], nB + 12288 + dstT);
  }
  bf16x8 af[4][2], bv0[2][2], bv1[2][2];
  for (int kt = 0; kt < nt; ++kt) {
    bf16_t* bufA = lds + (kt & 1) * 24576;
    bf16_t* bufB = bufA + 8192;
    bf16_t* nA = lds + ((kt + 1) & 1) * 24576;
    bf16_t* nB = nA + 8192;
    const int kn = (kt + 1 < nt ? kt + 1 : 0) << 6;
    const bf16_t* An = A + kn;
    const bf16_t* Bn = B + kn;
    VMW(2); BARR; FEN;
    readA8<0>(bufA, aBase, s0, s1, af);
    readB4<0>(bufB, bBase, s0, s1, bv0);
    async16(An + srcA[0], nA + dstT);
    async16(An + srcA[1], nA + 4096 + dstT);
    async16(Bn + srcB[0], nB + dstT);
    mfmaQ<4, 0, 0>(af, bv0, acc);
    VMW(3); BARR; FEN;
    readB4<1>(bufB, bBase, s0, s1, bv1);
    async16(Bn + srcB[1], nB + 4096 + dstT);
    async16(Bn + srcB[2], nB + 8192 + dstT);
    async16(Bn + srcB[3], nB + 12288 + dstT);
    mfmaQ<4, 0, 1>(af, bv1, acc);
  }
  VMW0;
  BARR;
}

// ===== R7's BK=32 core (qkvg: 2 blocks/CU) ==================================
template <int WM, int WN>
__device__ __forceinline__ void coreK32(const bf16_t* __restrict__ A, int lda,
                                        const bf16_t* __restrict__ B, int ldb, int nt,
                                        bf16_t* lds, f32x4 (&acc)[4][4]) {
  constexpr int T = WM * WN * 64;
  constexpr int AE = WM * 64 * 32;
  constexpr int BUF = AE + WN * 64 * 32;
  constexpr int NISS = BUF / (T * 8);
  const int t = threadIdx.x;
  const int lane = t & 63, w = t >> 6;
  const int wm = w / WN, wn = w % WN;
  const int lr = lane & 15, lg = lane >> 4;

  int aOff[4], bOff[4];
#pragma unroll
  for (int f = 0; f < 4; ++f) {
    int ra = wm * 64 + f * 16 + lr;
    aOff[f] = ra * 32 + (((lg + (ra >> 1)) & 3) << 3);
    int rb = wn * 64 + f * 16 + lr;
    bOff[f] = AE + rb * 32 + (((lg + (rb >> 1)) & 3) << 3);
  }
  int src[NISS];
#pragma unroll
  for (int q = 0; q < NISS; ++q) {
    int e = q * T * 8 + t * 8;
    bool isB = (q * T * 8) >= AE;
    int e2 = isB ? e - AE : e;
    int r = e2 >> 5;
    int g = (((e2 >> 3) & 3) - (r >> 1)) & 3;
    src[q] = r * (isB ? ldb : lda) + g * 8;
  }
#pragma unroll
  for (int m = 0; m < 4; ++m)
#pragma unroll
    for (int n = 0; n < 4; ++n) acc[m][n] = (f32x4){0.f, 0.f, 0.f, 0.f};

  {
    bf16_t* buf0 = lds;
#pragma unroll
    for (int q = 0; q < NISS; ++q) {
      bool isB = (q * T * 8) >= AE;
      async16((isB ? B : A) + src[q], buf0 + q * T * 8 + t * 8);
    }
  }
  VMW0; BARR; FEN;

  for (int tt = 0; tt < nt; ++tt) {
    bf16_t* cur = lds + (tt & 1) * BUF;
    bf16_t* nxt = lds + ((tt + 1) & 1) * BUF;
    const int kn = (tt + 1 < nt ? tt + 1 : 0) << 5;
#pragma unroll
    for (int q = 0; q < NISS; ++q) {
      bool isB = (q * T * 8) >= AE;
      async16((isB ? B : A) + kn + src[q], nxt + q * T * 8 + t * 8);
    }
    bf16x8 af[4], bv[4];
#pragma unroll
    for (int f = 0; f < 4; ++f) af[f] = *reinterpret_cast<const bf16x8*>(&cur[aOff[f]]);
#pragma unroll
    for (int f = 0; f < 4; ++f) bv[f] = *reinterpret_cast<const bf16x8*>(&cur[bOff[f]]);
    __builtin_amdgcn_s_setprio(1);
#pragma unroll
    for (int mf = 0; mf < 4; ++mf)
#pragma unroll
      for (int nf = 0; nf < 4; ++nf)
        acc[mf][nf] =
            __builtin_amdgcn_mfma_f32_16x16x32_bf16(af[mf], bv[nf], acc[mf][nf], 0, 0, 0);
    __builtin_amdgcn_s_setprio(0);
    VMW0; BARR; FEN;
  }
}

// --- elementwise convert f32 -> bf16 ---------------------------------------
__global__ void k_cvt(const float4* __restrict__ in, bf16x4* __restrict__ out, int n4) {
  int i = blockIdx.x * blockDim.x + threadIdx.x;
  if (i < n4) {
    float4 v = in[i];
    bf16x4 o;
    o[0] = (bf16_t)v.x; o[1] = (bf16_t)v.y; o[2] = (bf16_t)v.z; o[3] = (bf16_t)v.w;
    out[i] = o;
  }
}

// --- tiled transpose + convert f32[R][C] -> bf16[C][R] ----------------------
__global__ void k_tconv(const float* __restrict__ in, bf16_t* __restrict__ out,
                        int R, int C) {
  __shared__ bf16_t tile[64][65];
  int bc = blockIdx.x, br = blockIdx.y;
  int t = threadIdx.x;
  int c = t & 63, r0 = t >> 6;
#pragma unroll
  for (int rr = 0; rr < 64; rr += 4) {
    int r = rr + r0;
    tile[r][c] = (bf16_t)in[(long)(br * 64 + r) * C + bc * 64 + c];
  }
  __syncthreads();
#pragma unroll
  for (int rr = 0; rr < 64; rr += 4) {
    int r = rr + r0;
    out[(long)(bc * 64 + r) * R + br * 64 + c] = tile[c][r];
  }
}

// --- GEMM1: QKVG = hsb @ Wt^T + bias; sigmoid z==3; z==2 -> Vt (transposed) -
// tile 256x128 (coreK32<4,2>). grid 2048: xcd=i&7, g=i>>3.
__global__ __launch_bounds__(512, 4) void k_gemm_qkvg(
    const bf16_t* __restrict__ hsb, const bf16_t* __restrict__ Wt4,
    const float* __restrict__ bq, const float* __restrict__ bk,
    const float* __restrict__ bv, const float* __restrict__ bg,
    bf16_t* __restrict__ out, bf16_t* __restrict__ Vt) {
  extern __shared__ bf16_t lds[];
  const int SP = 136;   // row-major staging stride
  const int SPT = 264;  // transposed staging stride
  int i = blockIdx.x;
  int xcd = i & 7, g = i >> 3;
  int mb = g >> 3;             // 0..31 (256-row tiles)
  int nb = xcd * 8 + (g & 7);  // 0..63 (128-col tiles)
  f32x4 acc[4][4];
  coreK32<4, 2>(hsb + (long)mb * 256 * HID, HID, Wt4 + (long)nb * 128 * HID, HID,
                HID / 32, lds, acc);
  const int t = threadIdx.x, lane = t & 63, w = t >> 6;
  const int wm = w >> 1, wn = w & 1, lr = lane & 15, lg = lane >> 4;
  int z = nb >> 4;
  const float* bias = z == 0 ? bq : z == 1 ? bk : z == 2 ? bv : bg;
  int colT = (nb & 15) * 128;
  float b4[4];
#pragma unroll
  for (int nf = 0; nf < 4; ++nf) b4[nf] = bias[colT + wn * 64 + nf * 16 + lr];
  if (z != 2) {
    // row-major staging (256 x 136)
#pragma unroll
    for (int mf = 0; mf < 4; ++mf)
#pragma unroll
      for (int reg = 0; reg < 4; ++reg) {
        int lrow = wm * 64 + mf * 16 + lg * 4 + reg;
#pragma unroll
        for (int nf = 0; nf < 4; ++nf) {
          float v = acc[mf][nf][reg] + b4[nf];
          if (z == 3) v = 1.f / (1.f + __expf(-v));
          lds[lrow * SP + wn * 64 + nf * 16 + lr] = (bf16_t)v;
        }
      }
    __syncthreads();
    bf16_t* O = out + (long)z * BS * DD + (long)mb * 256 * DD + colT;
#pragma unroll
    for (int it = 0; it < 8; ++it) {
      int s = it * 512 + t;
      int row = s >> 4, sg = s & 15;
      bf16x8 v = *reinterpret_cast<const bf16x8*>(&lds[row * SP + sg * 8]);
      *reinterpret_cast<bf16x8*>(&O[(long)row * DD + sg * 8]) = v;
    }
  } else {
    // TRANSPOSED staging (128 x 264): ldsT[d][s]; write-bank stride 4 (free)
#pragma unroll
    for (int mf = 0; mf < 4; ++mf)
#pragma unroll
      for (int reg = 0; reg < 4; ++reg) {
        int lrow = wm * 64 + mf * 16 + lg * 4 + reg;
#pragma unroll
        for (int nf = 0; nf < 4; ++nf) {
          int d = wn * 64 + nf * 16 + lr;
          lds[d * SPT + lrow] = (bf16_t)(acc[mf][nf][reg] + b4[nf]);
        }
      }
    __syncthreads();
    int bz = mb >> 4, smb = mb & 15;
    bf16_t* Vd = Vt + ((long)bz * DD + colT) * SEQ + smb * 256;
    // copy-out: 128 d-rows x 512B, b128 reads (row-major in ldsT) — clean
#pragma unroll
    for (int it = 0; it < 8; ++it) {
      int s = it * 512 + t;
      int d = s >> 5, sg = s & 31;
      bf16x8 v = *reinterpret_cast<const bf16x8*>(&lds[d * SPT + sg * 8]);
      *reinterpret_cast<bf16x8*>(&Vd[(long)d * SEQ + sg * 8]) = v;
    }
  }
}

// --- pair (R3): P[row-chunk c][jt-tile] = Q K^T; fused diag softmax ---------
__global__ __launch_bounds__(512, 2) void k_pair(const bf16_t* __restrict__ Q,
                                                 const bf16_t* __restrict__ Kb,
                                                 bf16_t* __restrict__ P) {
  extern __shared__ bf16_t lds[];
  int p = blockIdx.x, b = blockIdx.y;
  int c = 0, base = 0;
  while (base + (c >> 1) + 1 <= p) { base += (c >> 1) + 1; ++c; }
  int jt = p - base;  // jt in [0, (c>>1)]
  f32x4 acc[4][4];
  core128(Q + ((long)b * SEQ + (long)c * 128) * DD, DD,
          Kb + ((long)b * SEQ + (long)jt * 256) * DD, DD, DD / 64, lds, acc);
  const int t = threadIdx.x, lane = t & 63, w = t >> 6;
  const int wm = w >> 2, wn = w & 3, lr = lane & 15, lg = lane >> 4;
  bf16_t* Pt = P + ((long)b * SEQ + (long)c * 128) * (long)SEQ + (long)jt * 256;
  const bool hasDiag = (jt == (c >> 1));
  const int side = c & 1;
  const float scale = 0.02209708691207961f;  // 1/sqrt(2048)
  float* smf = (float*)lds;  // core quiesced LDS
#pragma unroll
  for (int mf = 0; mf < 4; ++mf)
#pragma unroll
    for (int reg = 0; reg < 4; ++reg) {
      int row = wm * 64 + mf * 16 + lg * 4 + reg;
#pragma unroll
      for (int nf = 0; nf < 4; ++nf) {
        int col = wn * 64 + nf * 16 + lr;
        float v = acc[mf][nf][reg];
        if (hasDiag && ((col >> 7) == side)) {
          int cc = col & 127;
          float sv = v * scale;
          smf[row * 128 + ((cc + row) & 127)] = (cc <= row) ? sv : -1e30f;
        } else {
          if (hasDiag && side == 0 && (col >> 7) == 1) v = 0.f;  // future chunk
          Pt[(long)row * SEQ + col] = (bf16_t)v;
        }
      }
    }
  if (hasDiag) {
    __syncthreads();
    if (t < 128) {
      int r = t;
      float mx = -1e30f;
      for (int cc = 0; cc <= r; ++cc) mx = fmaxf(mx, smf[r * 128 + ((cc + r) & 127)]);
      float s = 0.f;
      for (int cc = 0; cc <= r; ++cc) s += __expf(smf[r * 128 + ((cc + r) & 127)] - mx);
      float inv = 1.f / s;
      for (int cc = 0; cc < 128; ++cc) {
        float v = (cc <= r) ? __expf(smf[r * 128 + ((cc + r) & 127)] - mx) * inv : 0.f;
        Pt[(long)r * SEQ + side * 128 + cc] = (bf16_t)v;
      }
    }
  }
}

// --- GEMM2 (R3): OutPre = (P @ V[0:K]) * gate, BM=128, longest-first --------
__global__ __launch_bounds__(512, 2) void k_gemm2(const bf16_t* __restrict__ P,
                                                  const bf16_t* __restrict__ Vt,
                                                  const bf16_t* __restrict__ G,
                                                  bf16_t* __restrict__ OutPre) {
  extern __shared__ bf16_t lds[];
  int bid = blockIdx.x;
  int mq = 31 - (bid >> 4);  // longest-first
  int r2 = bid & 15;
  int nb = r2 >> 1, b = r2 & 1;
  f32x4 acc[4][4];
  core128(P + ((long)b * SEQ + (long)mq * 128) * (long)SEQ, SEQ,
          Vt + (long)b * DD * SEQ + (long)nb * 256 * SEQ, SEQ, (mq + 1) * 2, lds, acc);
  const int t = threadIdx.x, lane = t & 63, w = t >> 6;
  const int wm = w >> 2, wn = w & 3, lr = lane & 15, lg = lane >> 4;
#pragma unroll
  for (int mf = 0; mf < 4; ++mf)
#pragma unroll
    for (int reg = 0; reg < 4; ++reg) {
      long row = (long)b * SEQ + (long)mq * 128 + wm * 64 + mf * 16 + lg * 4 + reg;
#pragma unroll
      for (int nf = 0; nf < 4; ++nf) {
        long idx = row * DD + nb * 256 + wn * 64 + nf * 16 + lr;
        float g = (float)G[idx];
        OutPre[idx] = (bf16_t)(acc[mf][nf][reg] * g);
      }
    }
}

// --- GEMM3 (R3): out = OutPre @ Wo + bo (f32 out), BM=128 -------------------
__global__ __launch_bounds__(512, 2) void k_gemm3(const bf16_t* __restrict__ OutPre,
                                                  const bf16_t* __restrict__ Wot,
                                                  const float* __restrict__ bo,
                                                  float* __restrict__ out) {
  extern __shared__ bf16_t lds[];
  int mb = blockIdx.x >> 2, nb = blockIdx.x & 3;
  f32x4 acc[4][4];
  core128(OutPre + (long)mb * 128 * DD, DD, Wot + (long)nb * 256 * DD, DD,
          DD / 64, lds, acc);
  const int t = threadIdx.x, lane = t & 63, w = t >> 6;
  const int wm = w >> 2, wn = w & 3, lr = lane & 15, lg = lane >> 4;
  int colbase = nb * 256 + wn * 64;
  float b4[4];
#pragma unroll
  for (int nf = 0; nf < 4; ++nf) b4[nf] = bo[colbase + nf * 16 + lr];
#pragma unroll
  for (int mf = 0; mf < 4; ++mf)
#pragma unroll
    for (int reg = 0; reg < 4; ++reg) {
      long row = mb * 128 + wm * 64 + mf * 16 + lg * 4 + reg;
#pragma unroll
      for (int nf = 0; nf < 4; ++nf)
        out[row * HID + colbase + nf * 16 + lr] = acc[mf][nf][reg] + b4[nf];
    }
}

extern "C" void kernel_launch(void* const* d_in, const int* in_sizes, int n_in,
                              void* d_out, int out_size, void* d_ws, size_t ws_size,
                              hipStream_t stream) {
  const float* hs = (const float*)d_in[0];
  const float* Wq = (const float*)d_in[1];
  const float* bq = (const float*)d_in[2];
  const float* Wk = (const float*)d_in[3];
  const float* bk = (const float*)d_in[4];
  const float* Wv = (const float*)d_in[5];
  const float* bv = (const float*)d_in[6];
  const float* Wg = (const float*)d_in[7];
  const float* bg = (const float*)d_in[8];
  const float* Wo = (const float*)d_in[9];
  const float* bo = (const float*)d_in[10];
  float* out = (float*)d_out;

  char* ws = (char*)d_ws;
  const size_t MB = 1024 * 1024;
  bf16_t* P = (bf16_t*)(ws);            // [2][4096][4096] bf16, 64MB
  bf16_t* hsb = (bf16_t*)(ws);          // aliases P (dead before pair)
  bf16_t* Wt4 = (bf16_t*)(ws + 16 * MB);
  bf16_t* Wot = (bf16_t*)(ws + 64 * MB);
  bf16_t* QKVG = (bf16_t*)(ws + 68 * MB);
  bf16_t* Vt = (bf16_t*)(ws + 196 * MB);

  bf16_t* Qb = QKVG;
  bf16_t* Kbuf = QKVG + (long)BS * DD;
  bf16_t* Vbuf = QKVG + 2l * BS * DD;  // V row-major unused (V -> Vt directly)
  bf16_t* Gbuf = QKVG + 3l * BS * DD;
  bf16_t* OutPre = Vbuf;

  hipFuncSetAttribute((const void*)k_gemm_qkvg,
                      hipFuncAttributeMaxDynamicSharedMemorySize, LDS_QKVG);
  hipFuncSetAttribute((const void*)k_pair,
                      hipFuncAttributeMaxDynamicSharedMemorySize, LDS_128);
  hipFuncSetAttribute((const void*)k_gemm2,
                      hipFuncAttributeMaxDynamicSharedMemorySize, LDS_128);
  hipFuncSetAttribute((const void*)k_gemm3,
                      hipFuncAttributeMaxDynamicSharedMemorySize, LDS_128);

  // 1. conversions
  k_cvt<<<(BS * HID / 4 + 255) / 256, 256, 0, stream>>>((const float4*)hs,
                                                        (bf16x4*)hsb, BS * HID / 4);
  k_tconv<<<dim3(DD / 64, HID / 64), 256, 0, stream>>>(Wq, Wt4 + 0l * DD * HID, HID, DD);
  k_tconv<<<dim3(DD / 64, HID / 64), 256, 0, stream>>>(Wk, Wt4 + 1l * DD * HID, HID, DD);
  k_tconv<<<dim3(DD / 64, HID / 64), 256, 0, stream>>>(Wv, Wt4 + 2l * DD * HID, HID, DD);
  k_tconv<<<dim3(DD / 64, HID / 64), 256, 0, stream>>>(Wg, Wt4 + 3l * DD * HID, HID, DD);
  k_tconv<<<dim3(HID / 64, DD / 64), 256, 0, stream>>>(Wo, Wot, DD, HID);

  // 2. QKVG projection (2048 blocks, 2 blk/CU; V fused -> Vt transposed)
  k_gemm_qkvg<<<2048, 512, LDS_QKVG, stream>>>(hsb, Wt4, bq, bk, bv, bg, QKVG, Vt);

  // 3. pairwise scores + fused diag softmax (544 uniform 128x256 blocks)
  k_pair<<<dim3(272, 2), 512, LDS_128, stream>>>(Qb, Kbuf, P);

  // 4. PV + gate (512 blocks, longest-first)
  k_gemm2<<<512, 512, LDS_128, stream>>>(P, Vt, Gbuf, OutPre);

  // 5. output projection (256 blocks)
  k_gemm3<<<256, 512, LDS_128, stream>>>(OutPre, Wot, bo, out);
}